// Round 14
// baseline (265.967 us; speedup 1.0000x reference)
//
#include <hip/hip_runtime.h>
#include <hip/hip_bf16.h>

// S4 (DPLR) forward, B=8 L=2048 IN=OUT=64 H=128 N=64, 4 layers.
// R30 = R29 + packed-FP32 Cauchy: the kfft Cauchy loop is instruction-count
// bound (~21 VALU/pole-freq * 64 poles * 4 freqs = 36us chip-wide issue floor).
// Rewritten on float2 ext-vectors with pre-negated coefficient pairs
// (u=(re,im), v=(im,-re), w3=(n11,-n11)) so hipcc can emit v_pk_fma_f32:
// 14 scalar fma -> 7 packed fma, ~21 -> ~12 slots. Per-lane math bit-identical
// (same fma tree/order) -> absmax unchanged. Pole table = 4 float4/pole (4KB,
// fits the 8KB ktmp overlay window); reads are wave-broadcast.
// omega via cosf/sinf on purpose (l=1024 bilinear singularity regularized by
// fp32 trig rounding).

#define Bsz 8
#define Lseq 2048
#define Hdim 128
#define Npol 64
#define NLAYERS 4

typedef __bf16 bf16x8 __attribute__((ext_vector_type(8)));
typedef float f32x16 __attribute__((ext_vector_type(16)));
typedef float f32x2 __attribute__((ext_vector_type(2)));

__device__ __forceinline__ float fast_rcp(float x) { return __builtin_amdgcn_rcpf(x); }
__device__ __forceinline__ float fast_rsq(float x) { return __builtin_amdgcn_rsqf(x); }

__device__ __forceinline__ float2 cmulf(float2 a, float2 b) {
    return make_float2(a.x * b.x - a.y * b.y, a.x * b.y + a.y * b.x);
}
__device__ __forceinline__ float2 cmulc(float2 a, float2 b) {  // a * conj(b)
    return make_float2(a.x * b.x + a.y * b.y, a.y * b.x - a.x * b.y);
}

__device__ __forceinline__ float gelu_f(float v) {
    float z = 0.7978845608028654f * (v + 0.044715f * v * v * v);
    float e = __expf(2.0f * z);
    return v - v * fast_rcp(e + 1.0f);
}

// XOR swizzle: strides 1/16/256 all conflict-uniform for the 4096 arrays.
__device__ __forceinline__ int sw(int i) { return (i & ~15) | ((i ^ (i >> 4)) & 15); }

static __device__ const float W16R[8] = {1.f, 0.9238795325f, 0.7071067812f, 0.3826834324f,
                                         0.f, -0.3826834324f, -0.7071067812f, -0.9238795325f};
static __device__ const float W16I[8] = {0.f, -0.3826834324f, -0.7071067812f, -0.9238795325f,
                                         -1.f, -0.9238795325f, -0.7071067812f, -0.3826834324f};
static __device__ const int BR4[16] = {0, 8, 4, 12, 2, 10, 6, 14, 1, 9, 5, 13, 3, 11, 7, 15};
static __device__ const int BR3[8] = {0, 4, 2, 6, 1, 5, 3, 7};

__device__ __forceinline__ float2 twget(const float2* __restrict__ tw, int e) {
    float2 w = tw[e & 2047];
    if (e & 2048) { w.x = -w.x; w.y = -w.y; }
    return w;
}

template <bool INV>
__device__ __forceinline__ void fft16_dif(float2 v[16]) {
#pragma unroll
    for (int mi = 0; mi < 4; mi++) {
        const int m = 8 >> mi;
#pragma unroll
        for (int g = 0; g < 16; g += 2 * m) {
#pragma unroll
            for (int j = 0; j < m; j++) {
                float wr = W16R[j << mi];
                float wi = INV ? -W16I[j << mi] : W16I[j << mi];
                float2 a = v[g + j], b = v[g + j + m];
                float dx = a.x - b.x, dy = a.y - b.y;
                v[g + j] = make_float2(a.x + b.x, a.y + b.y);
                v[g + j + m] = make_float2(dx * wr - dy * wi, dx * wi + dy * wr);
            }
        }
    }
}

template <bool INV>
__device__ __forceinline__ void fft16_dit(float2 v[16]) {
#pragma unroll
    for (int mi = 3; mi >= 0; mi--) {
        const int m = 8 >> mi;
#pragma unroll
        for (int g = 0; g < 16; g += 2 * m) {
#pragma unroll
            for (int j = 0; j < m; j++) {
                float wr = W16R[j << mi];
                float wi = INV ? -W16I[j << mi] : W16I[j << mi];
                float2 a = v[g + j], b = v[g + j + m];
                float bx = b.x * wr - b.y * wi, by = b.x * wi + b.y * wr;
                v[g + j] = make_float2(a.x + bx, a.y + by);
                v[g + j + m] = make_float2(a.x - bx, a.y - by);
            }
        }
    }
}

template <bool INV>
__device__ __forceinline__ void fft8_dif(float2 v[8]) {
#pragma unroll
    for (int mi = 0; mi < 3; mi++) {
        const int m = 4 >> mi;
#pragma unroll
        for (int g = 0; g < 8; g += 2 * m) {
#pragma unroll
            for (int j = 0; j < m; j++) {
                float wr = W16R[j << (mi + 1)];
                float wi = INV ? -W16I[j << (mi + 1)] : W16I[j << (mi + 1)];
                float2 a = v[g + j], b = v[g + j + m];
                float dx = a.x - b.x, dy = a.y - b.y;
                v[g + j] = make_float2(a.x + b.x, a.y + b.y);
                v[g + j + m] = make_float2(dx * wr - dy * wi, dx * wi + dy * wr);
            }
        }
    }
}

// Pass A of the zero-padded (upper half) forward 4096 FFT, input in registers.
__device__ __forceinline__ void fft4096_passA_hz(float2* data, const float2* __restrict__ tw,
                                                 int t, const float2 vin[8]) {
    float2 v[16];
#pragma unroll
    for (int j = 0; j < 8; j++) v[j] = vin[j];
#pragma unroll
    for (int j = 0; j < 8; j++)
        v[j + 8] = cmulf(v[j], make_float2(W16R[j], W16I[j]));
#pragma unroll
    for (int mi = 1; mi < 4; mi++) {
        const int m = 8 >> mi;
#pragma unroll
        for (int g = 0; g < 16; g += 2 * m) {
#pragma unroll
            for (int j = 0; j < m; j++) {
                float wr = W16R[j << mi], wi = W16I[j << mi];
                float2 a = v[g + j], b = v[g + j + m];
                float dx = a.x - b.x, dy = a.y - b.y;
                v[g + j] = make_float2(a.x + b.x, a.y + b.y);
                v[g + j + m] = make_float2(dx * wr - dy * wi, dx * wi + dy * wr);
            }
        }
    }
#pragma unroll
    for (int i = 1; i < 16; i++) v[i] = cmulf(v[i], twget(tw, t * BR4[i]));
#pragma unroll
    for (int i = 0; i < 16; i++) data[sw(i * 256 + t)] = v[i];
}

// Passes B and C of the forward 4096 FFT (256-thread t).
__device__ __forceinline__ void fft4096_fwd_B(float2* data, const float2* __restrict__ tw, int t) {
    int j0 = t & 15;
    int base = (t >> 4) * 256 + j0;
    float2 v[16];
#pragma unroll
    for (int k = 0; k < 16; k++) v[k] = data[sw(base + 16 * k)];
    fft16_dif<false>(v);
#pragma unroll
    for (int i = 1; i < 16; i++) v[i] = cmulf(v[i], twget(tw, 16 * j0 * BR4[i]));
#pragma unroll
    for (int i = 0; i < 16; i++) data[sw(base + 16 * i)] = v[i];
}
__device__ __forceinline__ void fft4096_fwd_C(float2* data, int t) {
    float2 v[16];
#pragma unroll
    for (int k = 0; k < 16; k++) v[k] = data[sw(t * 16 + k)];
    fft16_dif<false>(v);
#pragma unroll
    for (int i = 0; i < 16; i++) data[sw(t * 16 + i)] = v[i];
}

// ---------------- prep: twiddle + bf16 weights (w1,w2,dec_w,enc_w) ----------------
__global__ __launch_bounds__(256, 4) void prep_kernel(const float* __restrict__ w1,
                                                      const float* __restrict__ w2,
                                                      const float* __restrict__ dec_w,
                                                      const float* __restrict__ enc_w,
                                                      float2* __restrict__ tw,
                                                      __bf16* __restrict__ wbf,
                                                      __bf16* __restrict__ decbf,
                                                      __bf16* __restrict__ encbf) {
    int bid = blockIdx.x, t = threadIdx.x;
    if (bid < 8) {
        int k = bid * 256 + t;
        if (k < 2048) {
            double a = -6.283185307179586476925286766559 * (double)k / 4096.0;
            tw[k] = make_float2((float)cos(a), (float)sin(a));
        }
        return;
    }
    if (bid < 264) {
        int i = (bid - 8) * 256 + t;
        int layer = i >> 14, rem = i & 16383;
        wbf[((size_t)layer * 2) * 16384 + rem] = (__bf16)w1[i];
        wbf[((size_t)layer * 2 + 1) * 16384 + rem] = (__bf16)w2[i];
        return;
    }
    if (bid < 296) {  // dec_w (64x128) -> bf16
        int i = (bid - 264) * 256 + t;
        decbf[i] = (__bf16)dec_w[i];
        return;
    }
    // enc_w (128x64) -> bf16
    int i = (bid - 296) * 256 + t;
    encbf[i] = (__bf16)enc_w[i];
}

// ---------------- kfft (all layers, 512-thread blocks) + encoder merged ----------------
// kfft blocks [0,512): Kd[layer][h]; packed-f32 Cauchy on all 8 waves (4 freqs/
// thread), FFT phases guarded to their natural 128/256-thread widths (barriers
// outside guards). encoder blocks [512,1024): 256-thread code under t<256.
__global__ __launch_bounds__(512) void kfft_enc_kernel(float2* __restrict__ Kd1,
                                                       const float2* __restrict__ tw,
                                                       const float* __restrict__ x,
                                                       const __bf16* __restrict__ encbf,
                                                       const float* __restrict__ enc_b,
                                                       const float* __restrict__ nw,
                                                       const float* __restrict__ nb,
                                                       float* __restrict__ h,
                                                       float* __restrict__ hnT,
                                                       const float* __restrict__ lam_re,
                                                       const float* __restrict__ lam_im,
                                                       const float* __restrict__ p_re,
                                                       const float* __restrict__ p_im,
                                                       const float* __restrict__ b_re,
                                                       const float* __restrict__ b_im,
                                                       const float* __restrict__ c_re,
                                                       const float* __restrict__ c_im,
                                                       const float* __restrict__ log_step) {
    __shared__ __align__(16) float smem[10240];
    int bid = blockIdx.x, t = threadIdx.x;
    if (bid < 512) {
        int hh = bid & 127, layer = bid >> 7;
        int PN = Hdim * Npol;
        const float* lre = lam_re + layer * PN;
        const float* lim = lam_im + layer * PN;
        const float* pre = p_re + layer * PN;
        const float* pim = p_im + layer * PN;
        const float* bre = b_re + layer * PN;
        const float* bim = b_im + layer * PN;
        const float* cre = c_re + layer * PN;
        const float* cim = c_im + layer * PN;
        const float* lst = log_step + layer * Hdim;
        float2* data = (float2*)smem;            // floats [0,8192)
        // packed pole table (dead after Cauchy), 4 x float4[64] = 4KB:
        float4* pol0 = (float4*)(smem + 8192);   // (lam.x, lam.y, u0.x, u0.y)
        float4* pol1 = (float4*)(smem + 8448);   // (v0.x, v0.y, u1.x, u1.y)
        float4* pol2 = (float4*)(smem + 8704);   // (v1.x, v1.y, u2.x, u2.y)
        float4* pol3 = (float4*)(smem + 8960);   // (v2.x, v2.y, w3.x, w3.y)
        float* ktmp = smem + 8192;               // born after fft8 (overlay)
        int baseP = hh * Npol;
        if (t < Npol) {
            int n = t;
            float lr = lre[baseP + n], li = lim[baseP + n];
            float pr = pre[baseP + n], pi = pim[baseP + n];
            float br = bre[baseP + n], bi = bim[baseP + n];
            float cr = cre[baseP + n], ci = cim[baseP + n];
            float cbr = cr * br + ci * bi, cbi = cr * bi - ci * br;
            float cpr = cr * pr + ci * pi, cpi = cr * pi - ci * pr;
            float pbr = pr * br + pi * bi, pbi = pr * bi - pi * br;
            float n11 = pr * pr + pi * pi;
            pol0[n] = make_float4(lr, li, cbr, cbi);
            pol1[n] = make_float4(cbi, -cbr, cpr, cpi);
            pol2[n] = make_float4(cpi, -cpr, pbr, pbi);
            pol3[n] = make_float4(pbi, -pbr, n11, -n11);
        }
        __syncthreads();
        {   // ---- Cauchy spectrum: packed f32 pairs, 4 l-positions/thread ----
            float step = expf(lst[hh]);
            float gs = 2.0f / step;
            float wrv[4], wiv[4];
            f32x2 g[4];
#pragma unroll
            for (int j = 0; j < 4; j++) {
                int l = t + 512 * j;
                float ang = -6.283185307179586f * (float)l / (float)Lseq;
                float wr = cosf(ang), wi = sinf(ang);  // fp32 trig on purpose
                wrv[j] = wr; wiv[j] = wi;
                float dr = 1.0f + wr, di = wi;
                float invd2 = fast_rcp(dr * dr + di * di);
                float nr = 1.0f - wr, ni = -wi;
                g[j].x = gs * (nr * dr + ni * di) * invd2;
                g[j].y = gs * (ni * dr - nr * di) * invd2;
            }
            f32x2 a00[4], a01[4], a10[4], a11[4];
#pragma unroll
            for (int j = 0; j < 4; j++) {
                a00[j] = (f32x2)(0.f); a01[j] = (f32x2)(0.f);
                a10[j] = (f32x2)(0.f); a11[j] = (f32x2)(0.f);
            }
            for (int n = 0; n < Npol; n++) {
                float4 P0 = pol0[n];
                float4 P1 = pol1[n];
                float4 P2 = pol2[n];
                float4 P3 = pol3[n];
                f32x2 lam; lam.x = P0.x; lam.y = P0.y;
                f32x2 u0; u0.x = P0.z; u0.y = P0.w;
                f32x2 v0; v0.x = P1.x; v0.y = P1.y;
                f32x2 u1; u1.x = P1.z; u1.y = P1.w;
                f32x2 v1; v1.x = P2.x; v1.y = P2.y;
                f32x2 u2; u2.x = P2.z; u2.y = P2.w;
                f32x2 v2; v2.x = P3.x; v2.y = P3.y;
                f32x2 w3; w3.x = P3.z; w3.y = P3.w;
#pragma unroll
                for (int j = 0; j < 4; j++) {
                    f32x2 e = g[j] - lam;                       // pk_add(neg)
                    float inv2 = fast_rcp(fmaf(e.x, e.x, e.y * e.y));
                    f32x2 irmi = e * inv2;                      // pk_mul (broadcast)
                    f32x2 irb = (f32x2)(irmi.x);
                    f32x2 mib = (f32x2)(irmi.y);
                    a00[j] = u0 * irb + (v0 * mib + a00[j]);    // 2 pk_fma
                    a01[j] = u1 * irb + (v1 * mib + a01[j]);    // 2 pk_fma
                    a10[j] = u2 * irb + (v2 * mib + a10[j]);    // 2 pk_fma
                    a11[j] = w3 * irmi + a11[j];                // 1 pk_fma
                }
            }
#pragma unroll
            for (int j = 0; j < 4; j++) {
                int l = t + 512 * j;
                float dr = 1.0f + wrv[j], di = wiv[j];
                float invd2 = fast_rcp(dr * dr + di * di);
                float cr2 = 2.0f * dr * invd2, ci2 = -2.0f * di * invd2;
                float wr2 = 1.0f + a11[j].x, wi2 = a11[j].y;
                float w2inv = fast_rcp(fmaf(wr2, wr2, wi2 * wi2));
                float vr = wr2 * w2inv, vi = -wi2 * w2inv;
                float t1x = a01[j].x * a10[j].x - a01[j].y * a10[j].y;
                float t1y = a01[j].x * a10[j].y + a01[j].y * a10[j].x;
                float t2x = t1x * vr - t1y * vi, t2y = t1x * vi + t1y * vr;
                float ex = a00[j].x - t2x, ey = a00[j].y - t2y;
                data[sw(l)] = make_float2(cr2 * ex - ci2 * ey, cr2 * ey + ci2 * ex);
            }
        }
        __syncthreads();
        if (t < 128) {
            float2 v[16];
#pragma unroll
            for (int k = 0; k < 16; k++) v[k] = data[sw(t + 128 * k)];
            fft16_dif<true>(v);
#pragma unroll
            for (int i = 1; i < 16; i++) v[i] = cmulc(v[i], twget(tw, 2 * t * BR4[i]));
#pragma unroll
            for (int i = 0; i < 16; i++) data[sw(i * 128 + t)] = v[i];
        }
        __syncthreads();
        if (t < 128) {
            int i2 = t >> 3, j0 = t & 7;
            int base2 = i2 * 128 + j0;
            float2 v[16];
#pragma unroll
            for (int k = 0; k < 16; k++) v[k] = data[sw(base2 + 8 * k)];
            fft16_dif<true>(v);
#pragma unroll
            for (int i = 1; i < 16; i++) v[i] = cmulc(v[i], twget(tw, 32 * j0 * BR4[i]));
#pragma unroll
            for (int i = 0; i < 16; i++) data[sw(base2 + 8 * i)] = v[i];
        }
        __syncthreads();
        if (t < 256) {
            float2 v8[8];
#pragma unroll
            for (int k = 0; k < 8; k++) v8[k] = data[sw(t * 8 + k)];
            fft8_dif<true>(v8);
            int r = BR4[t >> 4], s = BR4[t & 15];
#pragma unroll
            for (int i = 0; i < 8; i++) {
                int l = r + 16 * s + 256 * BR3[i];
                ktmp[l] = v8[i].x * (1.0f / 2048.0f);
            }
        }
        __syncthreads();
        if (t < 256) {
            float2 vin[8];
#pragma unroll
            for (int k = 0; k < 8; k++) vin[k] = make_float2(ktmp[t + 256 * k], 0.f);
            fft4096_passA_hz(data, tw, t, vin);
        }
        __syncthreads();
        if (t < 256) fft4096_fwd_B(data, tw, t);
        __syncthreads();
        if (t < 256) fft4096_fwd_C(data, t);
        __syncthreads();
        float2* dst = Kd1 + ((size_t)layer * Hdim + hh) * 4096;
#pragma unroll
        for (int k = 0; k < 8; k++) {
            int p = t + 512 * k;
            dst[p] = data[sw(p)];
        }
    } else {
        // ---- encoder via bf16 MFMA + fused LN: 32 rows/block, t<256 active ----
        int r0 = (bid - 512) * 32;
        __bf16* ybf = (__bf16*)smem;              // 32*72 bf16
        float* dots = smem + 1152;                // 32*132 floats
        float2* mv = (float2*)(smem + 5376);      // 32 float2
        int bb = r0 >> 11, l0 = r0 & 2047;
        for (int i = t; i < 32 * 64; i += 512) {
            int r = i >> 6, k = i & 63;
            ybf[r * 72 + k] = (__bf16)x[(size_t)(r0 + r) * 64 + k];
        }
        __syncthreads();
        if (t < 256) {
            int wave = t >> 6, lane = t & 63;
            int m = lane & 31, half = lane >> 5;
            bf16x8 a[4];
#pragma unroll
            for (int kk = 0; kk < 4; kk++)
                a[kk] = *(const bf16x8*)&ybf[m * 72 + kk * 16 + half * 8];
            int o = 32 * wave + m;
            const __bf16* wr = encbf + (size_t)o * 64 + half * 8;
            f32x16 acc;
#pragma unroll
            for (int i = 0; i < 16; i++) acc[i] = 0.f;
#pragma unroll
            for (int kk = 0; kk < 4; kk++) {
                bf16x8 bw = *(const bf16x8*)(wr + kk * 16);
                acc = __builtin_amdgcn_mfma_f32_32x32x16_bf16(a[kk], bw, acc, 0, 0, 0);
            }
            float bo = enc_b[o];
#pragma unroll
            for (int reg = 0; reg < 16; reg++) {
                int row = (reg & 3) + 8 * (reg >> 2) + 4 * half;
                dots[row * 132 + o] = acc[reg] + bo;
            }
        }
        __syncthreads();
        if (t < 256) {
            int row = t >> 3, lane8 = t & 7;
            float s1 = 0.f, s2 = 0.f;
            int base = row * 132 + lane8 * 16;
#pragma unroll
            for (int q = 0; q < 4; q++) {
                float4 v4 = *(const float4*)&dots[base + 4 * q];
                s1 += v4.x + v4.y + v4.z + v4.w;
                s2 += v4.x * v4.x + v4.y * v4.y + v4.z * v4.z + v4.w * v4.w;
            }
#pragma unroll
            for (int mm = 1; mm < 8; mm <<= 1) { s1 += __shfl_xor(s1, mm); s2 += __shfl_xor(s2, mm); }
            if (lane8 == 0) {
                float mu = s1 * (1.0f / 128.0f);
                float var = s2 * (1.0f / 128.0f) - mu * mu;
                mv[row] = make_float2(mu, fast_rsq(var + 1e-5f));
            }
        }
        __syncthreads();
        if (t < 256) {
            int o2 = t & 127, rh = t >> 7;
            float nwc = nw[o2], nbc = nb[o2];
            float hnv[16];
#pragma unroll
            for (int j = 0; j < 16; j++) {
                int r = rh * 16 + j;
                float hvv = dots[r * 132 + o2];
                h[(size_t)(r0 + r) * Hdim + o2] = hvv;
                float2 mvv = mv[r];
                hnv[j] = (hvv - mvv.x) * mvv.y * nwc + nbc;
            }
            float* dst = hnT + ((size_t)bb * Hdim + o2) * Lseq + l0 + rh * 16;
            *(float4*)(dst)      = make_float4(hnv[0],  hnv[1],  hnv[2],  hnv[3]);
            *(float4*)(dst + 4)  = make_float4(hnv[4],  hnv[5],  hnv[6],  hnv[7]);
            *(float4*)(dst + 8)  = make_float4(hnv[8],  hnv[9],  hnv[10], hnv[11]);
            *(float4*)(dst + 12) = make_float4(hnv[12], hnv[13], hnv[14], hnv[15]);
        }
    }
}

// ---------------- FFT convolution: batch-pair packing, radix-16^3 ----------------
// Output y written as bf16 (its only consumer is the MLP's bf16 A-operand).
__global__ __launch_bounds__(256) void conv_kernel(const float* __restrict__ hnT,
                                                   __bf16* __restrict__ ybuf,
                                                   const float2* __restrict__ Kd1,
                                                   const float* __restrict__ dvec,
                                                   const float2* __restrict__ tw) {
    int h = blockIdx.x, bp = blockIdx.y, t = threadIdx.x;
    __shared__ float2 data[4096];
    const float* u0 = hnT + ((size_t)(2 * bp) * Hdim + h) * Lseq;
    const float* u1 = hnT + ((size_t)(2 * bp + 1) * Hdim + h) * Lseq;
    __bf16* y0 = ybuf + ((size_t)(2 * bp) * Hdim + h) * Lseq;
    __bf16* y1 = ybuf + ((size_t)(2 * bp + 1) * Hdim + h) * Lseq;
    float2 ureg[8];
    float2 Kreg[16];
    float2 twB[15];
    const int j0 = t & 15;
    const float4* Kp4 = (const float4*)(Kd1 + (size_t)h * 4096 + t * 16);
    {   // pruned pass A: input upper half zero, from registers. Kd + B-twiddle
        // prefetch issued alongside the u loads so latency hides under the fwd FFT.
        float2 vin[8];
#pragma unroll
        for (int k = 0; k < 8; k++) {
            int l = t + 256 * k;
            float2 u2 = make_float2(u0[l], u1[l]);
            ureg[k] = u2;
            vin[k] = u2;
        }
#pragma unroll
        for (int k = 0; k < 8; k++) {
            float4 q = Kp4[k];
            Kreg[2 * k]     = make_float2(q.x, q.y);
            Kreg[2 * k + 1] = make_float2(q.z, q.w);
        }
#pragma unroll
        for (int i = 1; i < 16; i++) twB[i - 1] = twget(tw, 16 * j0 * BR4[i]);
        fft4096_passA_hz(data, tw, t, vin);
    }
    __syncthreads();
    {   // forward pass B (register twiddles)
        int base = (t >> 4) * 256 + j0;
        float2 v[16];
#pragma unroll
        for (int k = 0; k < 16; k++) v[k] = data[sw(base + 16 * k)];
        fft16_dif<false>(v);
#pragma unroll
        for (int i = 1; i < 16; i++) v[i] = cmulf(v[i], twB[i - 1]);
#pragma unroll
        for (int i = 0; i < 16; i++) data[sw(base + 16 * i)] = v[i];
    }
    __syncthreads();
    {   // fused: forward pass C -> pointwise *Kd*scale -> inverse pass C'
        const float scale = 1.0f / 4096.0f;
        float2 v[16];
#pragma unroll
        for (int k = 0; k < 16; k++) v[k] = data[sw(t * 16 + k)];
        fft16_dif<false>(v);
#pragma unroll
        for (int i = 0; i < 16; i++) {
            float2 W = cmulf(v[i], Kreg[i]);
            v[i] = make_float2(W.x * scale, W.y * scale);
        }
        fft16_dit<true>(v);
#pragma unroll
        for (int i = 0; i < 16; i++) data[sw(t * 16 + i)] = v[i];
    }
    __syncthreads();
    {   // inverse pass B' (register twiddles, conjugated)
        int base2 = (t >> 4) * 256 + j0;
        float2 v[16];
        v[0] = data[sw(base2)];
#pragma unroll
        for (int i = 1; i < 16; i++)
            v[i] = cmulc(data[sw(base2 + 16 * i)], twB[i - 1]);
        fft16_dit<true>(v);
#pragma unroll
        for (int i = 0; i < 16; i++) data[sw(base2 + 16 * i)] = v[i];
    }
    __syncthreads();
    {   // inverse pass A': final stage pruned to the needed output half (l < 2048)
        float2 v[16];
        v[0] = data[sw(t)];
#pragma unroll
        for (int i = 1; i < 16; i++)
            v[i] = cmulc(data[sw(i * 256 + t)], twget(tw, t * BR4[i]));
#pragma unroll
        for (int mi = 3; mi >= 1; mi--) {
            const int m = 8 >> mi;
#pragma unroll
            for (int g = 0; g < 16; g += 2 * m) {
#pragma unroll
                for (int j = 0; j < m; j++) {
                    float wr = W16R[j << mi], wi = -W16I[j << mi];
                    float2 a = v[g + j], bb2 = v[g + j + m];
                    float bx = bb2.x * wr - bb2.y * wi, by = bb2.x * wi + bb2.y * wr;
                    v[g + j] = make_float2(a.x + bx, a.y + by);
                    v[g + j + m] = make_float2(a.x - bx, a.y - by);
                }
            }
        }
#pragma unroll
        for (int j = 0; j < 8; j++) {
            float wr = W16R[j], wi = -W16I[j];
            float2 bb2 = v[j + 8];
            float bx = bb2.x * wr - bb2.y * wi, by = bb2.x * wi + bb2.y * wr;
            v[j] = make_float2(v[j].x + bx, v[j].y + by);
        }
        float dcoef = dvec[h];
#pragma unroll
        for (int k = 0; k < 8; k++) {
            int l = t + 256 * k;
            y0[l] = (__bf16)gelu_f(v[k].x + ureg[k].x * dcoef);
            y1[l] = (__bf16)gelu_f(v[k].y + ureg[k].y * dcoef);
        }
    }
}

// ---------------- gated MLP via bf16 MFMA + residual + fused LN: 32 rows/block ----------------
__global__ __launch_bounds__(256) void mlp_kernel(const __bf16* __restrict__ yT,
                                                  float* __restrict__ h,
                                                  float* __restrict__ hnT,
                                                  const __bf16* __restrict__ w1b,
                                                  const __bf16* __restrict__ w2b,
                                                  const float* __restrict__ b1,
                                                  const float* __restrict__ b2,
                                                  const float* __restrict__ nw,
                                                  const float* __restrict__ nb) {
    int r0 = blockIdx.x * 32;
    int t = threadIdx.x;
    int wave = t >> 6, lane = t & 63;
    __shared__ __align__(16) __bf16 ybf[32 * 136];
    __shared__ float dots[32 * 132];
    __shared__ float2 mv[32];
    int bb = r0 >> 11, l0 = r0 & 2047;
    for (int i = t; i < 32 * 128; i += 256) {
        int r = i & 31, k = i >> 5;
        ybf[r * 136 + k] = yT[((size_t)bb * Hdim + k) * Lseq + l0 + r];
    }
    __syncthreads();
    int m = lane & 31, half = lane >> 5;
    bf16x8 a[8];
#pragma unroll
    for (int kk = 0; kk < 8; kk++)
        a[kk] = *(const bf16x8*)&ybf[m * 136 + kk * 16 + half * 8];
    int out = 32 * wave + m;
    const __bf16* w1r = w1b + (size_t)out * 128 + half * 8;
    const __bf16* w2r = w2b + (size_t)out * 128 + half * 8;
    f32x16 acc1, acc2;
#pragma unroll
    for (int i = 0; i < 16; i++) { acc1[i] = 0.f; acc2[i] = 0.f; }
#pragma unroll
    for (int kk = 0; kk < 8; kk++) {
        bf16x8 bw1 = *(const bf16x8*)(w1r + kk * 16);
        bf16x8 bw2 = *(const bf16x8*)(w2r + kk * 16);
        acc1 = __builtin_amdgcn_mfma_f32_32x32x16_bf16(a[kk], bw1, acc1, 0, 0, 0);
        acc2 = __builtin_amdgcn_mfma_f32_32x32x16_bf16(a[kk], bw2, acc2, 0, 0, 0);
    }
    float bias1 = b1[out], bias2 = b2[out];
#pragma unroll
    for (int reg = 0; reg < 16; reg++) {
        int row = (reg & 3) + 8 * (reg >> 2) + 4 * half;
        float v1 = acc1[reg] + bias1;
        float v2 = acc2[reg] + bias2;
        float g = fast_rcp(1.0f + __expf(-v2));
        float hv = h[(size_t)(r0 + row) * Hdim + out] + v1 * g;
        dots[row * 132 + out] = hv;
    }
    __syncthreads();
    {
        int row = t >> 3, lane8 = t & 7;
        float s1 = 0.f, s2 = 0.f;
        int base = row * 132 + lane8 * 16;
#pragma unroll
        for (int q = 0; q < 4; q++) {
            float4 v4 = *(const float4*)&dots[base + 4 * q];
            s1 += v4.x + v4.y + v4.z + v4.w;
            s2 += v4.x * v4.x + v4.y * v4.y + v4.z * v4.z + v4.w * v4.w;
        }
#pragma unroll
        for (int mm = 1; mm < 8; mm <<= 1) { s1 += __shfl_xor(s1, mm); s2 += __shfl_xor(s2, mm); }
        if (lane8 == 0) {
            float mu = s1 * (1.0f / 128.0f);
            float var = s2 * (1.0f / 128.0f) - mu * mu;
            mv[row] = make_float2(mu, fast_rsq(var + 1e-5f));
        }
    }
    __syncthreads();
    {
        int o = t & 127, rh = t >> 7;
        float nwc = nw[o], nbc = nb[o];
        float hnv[16];
#pragma unroll
        for (int j = 0; j < 16; j++) {
            int r = rh * 16 + j;
            float hvv = dots[r * 132 + o];
            h[(size_t)(r0 + r) * Hdim + o] = hvv;
            float2 mvv = mv[r];
            hnv[j] = (hvv - mvv.x) * mvv.y * nwc + nbc;
        }
        float* dst = hnT + ((size_t)bb * Hdim + o) * Lseq + l0 + rh * 16;
        *(float4*)(dst)      = make_float4(hnv[0],  hnv[1],  hnv[2],  hnv[3]);
        *(float4*)(dst + 4)  = make_float4(hnv[4],  hnv[5],  hnv[6],  hnv[7]);
        *(float4*)(dst + 8)  = make_float4(hnv[8],  hnv[9],  hnv[10], hnv[11]);
        *(float4*)(dst + 12) = make_float4(hnv[12], hnv[13], hnv[14], hnv[15]);
    }
}

// ---------------- last layer: gated MLP + residual + fused DECODER (bf16 MFMA) ----------
__global__ __launch_bounds__(256) void mlpdec_kernel(const __bf16* __restrict__ yT,
                                                     const float* __restrict__ h,
                                                     const __bf16* __restrict__ w1b,
                                                     const __bf16* __restrict__ w2b,
                                                     const float* __restrict__ b1,
                                                     const float* __restrict__ b2,
                                                     const __bf16* __restrict__ decb,
                                                     const float* __restrict__ dec_bias,
                                                     float* __restrict__ out) {
    int r0 = blockIdx.x * 32;
    int t = threadIdx.x;
    int wave = t >> 6, lane = t & 63;
    __shared__ __align__(16) __bf16 ybf[32 * 136];
    __shared__ float dots[32 * 132];
    int bb = r0 >> 11, l0 = r0 & 2047;
    for (int i = t; i < 32 * 128; i += 256) {
        int r = i & 31, k = i >> 5;
        ybf[r * 136 + k] = yT[((size_t)bb * Hdim + k) * Lseq + l0 + r];
    }
    __syncthreads();
    int m = lane & 31, half = lane >> 5;
    bf16x8 a[8];
#pragma unroll
    for (int kk = 0; kk < 8; kk++)
        a[kk] = *(const bf16x8*)&ybf[m * 136 + kk * 16 + half * 8];
    int outc = 32 * wave + m;
    const __bf16* w1r = w1b + (size_t)outc * 128 + half * 8;
    const __bf16* w2r = w2b + (size_t)outc * 128 + half * 8;
    f32x16 acc1, acc2;
#pragma unroll
    for (int i = 0; i < 16; i++) { acc1[i] = 0.f; acc2[i] = 0.f; }
#pragma unroll
    for (int kk = 0; kk < 8; kk++) {
        bf16x8 bw1 = *(const bf16x8*)(w1r + kk * 16);
        bf16x8 bw2 = *(const bf16x8*)(w2r + kk * 16);
        acc1 = __builtin_amdgcn_mfma_f32_32x32x16_bf16(a[kk], bw1, acc1, 0, 0, 0);
        acc2 = __builtin_amdgcn_mfma_f32_32x32x16_bf16(a[kk], bw2, acc2, 0, 0, 0);
    }
    float bias1 = b1[outc], bias2 = b2[outc];
#pragma unroll
    for (int reg = 0; reg < 16; reg++) {
        int row = (reg & 3) + 8 * (reg >> 2) + 4 * half;
        float v1 = acc1[reg] + bias1;
        float v2 = acc2[reg] + bias2;
        float g = fast_rcp(1.0f + __expf(-v2));
        float hv = h[(size_t)(r0 + row) * Hdim + outc] + v1 * g;
        dots[row * 132 + outc] = hv;
    }
    __syncthreads();
    // restage h tile as bf16 A-operands
    for (int i = t; i < 32 * 128; i += 256) {
        int r = i >> 7, k = i & 127;
        ybf[r * 136 + k] = (__bf16)dots[r * 132 + k];
    }
    __syncthreads();
    if (wave < 2) {  // decoder GEMM: 32 rows x 64 outs, K=128
        bf16x8 a2[8];
#pragma unroll
        for (int kk = 0; kk < 8; kk++)
            a2[kk] = *(const bf16x8*)&ybf[m * 136 + kk * 16 + half * 8];
        int oc = 32 * wave + m;  // 0..63
        const __bf16* wr = decb + (size_t)oc * 128 + half * 8;
        f32x16 acc;
#pragma unroll
        for (int i = 0; i < 16; i++) acc[i] = 0.f;
#pragma unroll
        for (int kk = 0; kk < 8; kk++) {
            bf16x8 bw = *(const bf16x8*)(wr + kk * 16);
            acc = __builtin_amdgcn_mfma_f32_32x32x16_bf16(a2[kk], bw, acc, 0, 0, 0);
        }
        float bo = dec_bias[oc];
#pragma unroll
        for (int reg = 0; reg < 16; reg++) {
            int row = (reg & 3) + 8 * (reg >> 2) + 4 * half;
            out[(size_t)(r0 + row) * 64 + oc] = acc[reg] + bo;
        }
    }
}

extern "C" void kernel_launch(void* const* d_in, const int* in_sizes, int n_in,
                              void* d_out, int out_size, void* d_ws, size_t ws_size,
                              hipStream_t stream) {
    const float* x      = (const float*)d_in[0];
    const float* enc_w  = (const float*)d_in[2];
    const float* enc_b  = (const float*)d_in[3];
    const float* dec_w  = (const float*)d_in[4];
    const float* dec_b  = (const float*)d_in[5];
    const float* lam_re = (const float*)d_in[6];
    const float* lam_im = (const float*)d_in[7];
    const float* p_re   = (const float*)d_in[8];
    const float* p_im   = (const float*)d_in[9];
    const float* b_re   = (const float*)d_in[10];
    const float* b_im   = (const float*)d_in[11];
    const float* c_re   = (const float*)d_in[12];
    const float* c_im   = (const float*)d_in[13];
    const float* dvec   = (const float*)d_in[14];
    const float* lstep  = (const float*)d_in[15];
    const float* norm_w = (const float*)d_in[16];
    const float* norm_b = (const float*)d_in[17];
    const float* w1     = (const float*)d_in[18];
    const float* b1     = (const float*)d_in[19];
    const float* w2     = (const float*)d_in[20];
    const float* b2     = (const float*)d_in[21];
    float* out = (float*)d_out;

    char* ws = (char*)d_ws;
    float2* tw  = (float2*)ws;  ws += 2048 * sizeof(float2);
    float*  h   = (float*)ws;   ws += (size_t)Bsz * Lseq * Hdim * sizeof(float);
    float*  hnT = (float*)ws;   ws += (size_t)Bsz * Lseq * Hdim * sizeof(float);
    __bf16* ybuf = (__bf16*)ws; ws += (size_t)Bsz * Lseq * Hdim * sizeof(__bf16);
    float2* Kd1 = (float2*)ws;  ws += (size_t)NLAYERS * Hdim * 4096 * sizeof(float2);
    __bf16* wbf = (__bf16*)ws;  ws += (size_t)NLAYERS * 2 * Hdim * Hdim * sizeof(__bf16);
    __bf16* dbf = (__bf16*)ws;  ws += (size_t)64 * Hdim * sizeof(__bf16);
    __bf16* ebf = (__bf16*)ws;  ws += (size_t)Hdim * 64 * sizeof(__bf16);

    const int nrows = Bsz * Lseq;  // 16384

    prep_kernel<<<328, 256, 0, stream>>>(w1, w2, dec_w, enc_w, tw, wbf, dbf, ebf);
    kfft_enc_kernel<<<512 + nrows / 32, 512, 0, stream>>>(
        Kd1, tw, x, ebf, enc_b, norm_w, norm_b, h, hnT,
        lam_re, lam_im, p_re, p_im, b_re, b_im, c_re, c_im, lstep);
    for (int L = 0; L < NLAYERS; L++) {
        conv_kernel<<<dim3(Hdim, Bsz / 2), 256, 0, stream>>>(
            hnT, ybuf, Kd1 + (size_t)L * Hdim * 4096, dvec + L * Hdim, tw);
        const __bf16* w1bL = wbf + (size_t)L * 2 * Hdim * Hdim;
        const __bf16* w2bL = w1bL + Hdim * Hdim;
        if (L < NLAYERS - 1) {
            const float* nwn = norm_w + (L + 1) * Hdim;
            const float* nbn = norm_b + (L + 1) * Hdim;
            mlp_kernel<<<nrows / 32, 256, 0, stream>>>(ybuf, h, hnT, w1bL, w2bL,
                                                       b1 + L * Hdim, b2 + L * Hdim,
                                                       nwn, nbn);
        } else {
            mlpdec_kernel<<<nrows / 32, 256, 0, stream>>>(ybuf, h, w1bL, w2bL,
                                                          b1 + L * Hdim, b2 + L * Hdim,
                                                          dbf, dec_b, out);
        }
    }
}

// Round 16
// 264.130 us; speedup vs baseline: 1.0070x; 1.0070x over previous
//
#include <hip/hip_runtime.h>
#include <hip/hip_bf16.h>

// S4 (DPLR) forward, B=8 L=2048 IN=OUT=64 H=128 N=64, 4 layers.
// R32 = R31 resubmitted verbatim (two consecutive container-acquisition
// failures; kernel itself never ran). Changes vs R30: mlp/mlpdec rebuilt on
// 512 threads — the two gated-MLP GEMMs split across 8 waves (waves 0-3: w1,
// waves 4-7: w2 into a second LDS dots array), halving per-wave MFMA latency
// and doubling waves/CU (8->16 on a grid-limited kernel). Gate+residual runs
// as a separate phase (same op order -> bit-identical); LN reduce + hnT write
// keep their exact 256-thread code under t<256. kfft_enc/conv/prep
// byte-identical to R30. omega via cosf/sinf on purpose (l=1024 bilinear
// singularity regularized by fp32 trig rounding).

#define Bsz 8
#define Lseq 2048
#define Hdim 128
#define Npol 64
#define NLAYERS 4

typedef __bf16 bf16x8 __attribute__((ext_vector_type(8)));
typedef float f32x16 __attribute__((ext_vector_type(16)));
typedef float f32x2 __attribute__((ext_vector_type(2)));

__device__ __forceinline__ float fast_rcp(float x) { return __builtin_amdgcn_rcpf(x); }
__device__ __forceinline__ float fast_rsq(float x) { return __builtin_amdgcn_rsqf(x); }

__device__ __forceinline__ float2 cmulf(float2 a, float2 b) {
    return make_float2(a.x * b.x - a.y * b.y, a.x * b.y + a.y * b.x);
}
__device__ __forceinline__ float2 cmulc(float2 a, float2 b) {  // a * conj(b)
    return make_float2(a.x * b.x + a.y * b.y, a.y * b.x - a.x * b.y);
}

__device__ __forceinline__ float gelu_f(float v) {
    float z = 0.7978845608028654f * (v + 0.044715f * v * v * v);
    float e = __expf(2.0f * z);
    return v - v * fast_rcp(e + 1.0f);
}

// XOR swizzle: strides 1/16/256 all conflict-uniform for the 4096 arrays.
__device__ __forceinline__ int sw(int i) { return (i & ~15) | ((i ^ (i >> 4)) & 15); }

static __device__ const float W16R[8] = {1.f, 0.9238795325f, 0.7071067812f, 0.3826834324f,
                                         0.f, -0.3826834324f, -0.7071067812f, -0.9238795325f};
static __device__ const float W16I[8] = {0.f, -0.3826834324f, -0.7071067812f, -0.9238795325f,
                                         -1.f, -0.9238795325f, -0.7071067812f, -0.3826834324f};
static __device__ const int BR4[16] = {0, 8, 4, 12, 2, 10, 6, 14, 1, 9, 5, 13, 3, 11, 7, 15};
static __device__ const int BR3[8] = {0, 4, 2, 6, 1, 5, 3, 7};

__device__ __forceinline__ float2 twget(const float2* __restrict__ tw, int e) {
    float2 w = tw[e & 2047];
    if (e & 2048) { w.x = -w.x; w.y = -w.y; }
    return w;
}

template <bool INV>
__device__ __forceinline__ void fft16_dif(float2 v[16]) {
#pragma unroll
    for (int mi = 0; mi < 4; mi++) {
        const int m = 8 >> mi;
#pragma unroll
        for (int g = 0; g < 16; g += 2 * m) {
#pragma unroll
            for (int j = 0; j < m; j++) {
                float wr = W16R[j << mi];
                float wi = INV ? -W16I[j << mi] : W16I[j << mi];
                float2 a = v[g + j], b = v[g + j + m];
                float dx = a.x - b.x, dy = a.y - b.y;
                v[g + j] = make_float2(a.x + b.x, a.y + b.y);
                v[g + j + m] = make_float2(dx * wr - dy * wi, dx * wi + dy * wr);
            }
        }
    }
}

template <bool INV>
__device__ __forceinline__ void fft16_dit(float2 v[16]) {
#pragma unroll
    for (int mi = 3; mi >= 0; mi--) {
        const int m = 8 >> mi;
#pragma unroll
        for (int g = 0; g < 16; g += 2 * m) {
#pragma unroll
            for (int j = 0; j < m; j++) {
                float wr = W16R[j << mi];
                float wi = INV ? -W16I[j << mi] : W16I[j << mi];
                float2 a = v[g + j], b = v[g + j + m];
                float bx = b.x * wr - b.y * wi, by = b.x * wi + b.y * wr;
                v[g + j] = make_float2(a.x + bx, a.y + by);
                v[g + j + m] = make_float2(a.x - bx, a.y - by);
            }
        }
    }
}

template <bool INV>
__device__ __forceinline__ void fft8_dif(float2 v[8]) {
#pragma unroll
    for (int mi = 0; mi < 3; mi++) {
        const int m = 4 >> mi;
#pragma unroll
        for (int g = 0; g < 8; g += 2 * m) {
#pragma unroll
            for (int j = 0; j < m; j++) {
                float wr = W16R[j << (mi + 1)];
                float wi = INV ? -W16I[j << (mi + 1)] : W16I[j << (mi + 1)];
                float2 a = v[g + j], b = v[g + j + m];
                float dx = a.x - b.x, dy = a.y - b.y;
                v[g + j] = make_float2(a.x + b.x, a.y + b.y);
                v[g + j + m] = make_float2(dx * wr - dy * wi, dx * wi + dy * wr);
            }
        }
    }
}

// Pass A of the zero-padded (upper half) forward 4096 FFT, input in registers.
__device__ __forceinline__ void fft4096_passA_hz(float2* data, const float2* __restrict__ tw,
                                                 int t, const float2 vin[8]) {
    float2 v[16];
#pragma unroll
    for (int j = 0; j < 8; j++) v[j] = vin[j];
#pragma unroll
    for (int j = 0; j < 8; j++)
        v[j + 8] = cmulf(v[j], make_float2(W16R[j], W16I[j]));
#pragma unroll
    for (int mi = 1; mi < 4; mi++) {
        const int m = 8 >> mi;
#pragma unroll
        for (int g = 0; g < 16; g += 2 * m) {
#pragma unroll
            for (int j = 0; j < m; j++) {
                float wr = W16R[j << mi], wi = W16I[j << mi];
                float2 a = v[g + j], b = v[g + j + m];
                float dx = a.x - b.x, dy = a.y - b.y;
                v[g + j] = make_float2(a.x + b.x, a.y + b.y);
                v[g + j + m] = make_float2(dx * wr - dy * wi, dx * wi + dy * wr);
            }
        }
    }
#pragma unroll
    for (int i = 1; i < 16; i++) v[i] = cmulf(v[i], twget(tw, t * BR4[i]));
#pragma unroll
    for (int i = 0; i < 16; i++) data[sw(i * 256 + t)] = v[i];
}

// Passes B and C of the forward 4096 FFT (256-thread t).
__device__ __forceinline__ void fft4096_fwd_B(float2* data, const float2* __restrict__ tw, int t) {
    int j0 = t & 15;
    int base = (t >> 4) * 256 + j0;
    float2 v[16];
#pragma unroll
    for (int k = 0; k < 16; k++) v[k] = data[sw(base + 16 * k)];
    fft16_dif<false>(v);
#pragma unroll
    for (int i = 1; i < 16; i++) v[i] = cmulf(v[i], twget(tw, 16 * j0 * BR4[i]));
#pragma unroll
    for (int i = 0; i < 16; i++) data[sw(base + 16 * i)] = v[i];
}
__device__ __forceinline__ void fft4096_fwd_C(float2* data, int t) {
    float2 v[16];
#pragma unroll
    for (int k = 0; k < 16; k++) v[k] = data[sw(t * 16 + k)];
    fft16_dif<false>(v);
#pragma unroll
    for (int i = 0; i < 16; i++) data[sw(t * 16 + i)] = v[i];
}

// ---------------- prep: twiddle + bf16 weights (w1,w2,dec_w,enc_w) ----------------
__global__ __launch_bounds__(256, 4) void prep_kernel(const float* __restrict__ w1,
                                                      const float* __restrict__ w2,
                                                      const float* __restrict__ dec_w,
                                                      const float* __restrict__ enc_w,
                                                      float2* __restrict__ tw,
                                                      __bf16* __restrict__ wbf,
                                                      __bf16* __restrict__ decbf,
                                                      __bf16* __restrict__ encbf) {
    int bid = blockIdx.x, t = threadIdx.x;
    if (bid < 8) {
        int k = bid * 256 + t;
        if (k < 2048) {
            double a = -6.283185307179586476925286766559 * (double)k / 4096.0;
            tw[k] = make_float2((float)cos(a), (float)sin(a));
        }
        return;
    }
    if (bid < 264) {
        int i = (bid - 8) * 256 + t;
        int layer = i >> 14, rem = i & 16383;
        wbf[((size_t)layer * 2) * 16384 + rem] = (__bf16)w1[i];
        wbf[((size_t)layer * 2 + 1) * 16384 + rem] = (__bf16)w2[i];
        return;
    }
    if (bid < 296) {  // dec_w (64x128) -> bf16
        int i = (bid - 264) * 256 + t;
        decbf[i] = (__bf16)dec_w[i];
        return;
    }
    // enc_w (128x64) -> bf16
    int i = (bid - 296) * 256 + t;
    encbf[i] = (__bf16)enc_w[i];
}

// ---------------- kfft (all layers, 512-thread blocks) + encoder merged ----------------
__global__ __launch_bounds__(512) void kfft_enc_kernel(float2* __restrict__ Kd1,
                                                       const float2* __restrict__ tw,
                                                       const float* __restrict__ x,
                                                       const __bf16* __restrict__ encbf,
                                                       const float* __restrict__ enc_b,
                                                       const float* __restrict__ nw,
                                                       const float* __restrict__ nb,
                                                       float* __restrict__ h,
                                                       float* __restrict__ hnT,
                                                       const float* __restrict__ lam_re,
                                                       const float* __restrict__ lam_im,
                                                       const float* __restrict__ p_re,
                                                       const float* __restrict__ p_im,
                                                       const float* __restrict__ b_re,
                                                       const float* __restrict__ b_im,
                                                       const float* __restrict__ c_re,
                                                       const float* __restrict__ c_im,
                                                       const float* __restrict__ log_step) {
    __shared__ __align__(16) float smem[10240];
    int bid = blockIdx.x, t = threadIdx.x;
    if (bid < 512) {
        int hh = bid & 127, layer = bid >> 7;
        int PN = Hdim * Npol;
        const float* lre = lam_re + layer * PN;
        const float* lim = lam_im + layer * PN;
        const float* pre = p_re + layer * PN;
        const float* pim = p_im + layer * PN;
        const float* bre = b_re + layer * PN;
        const float* bim = b_im + layer * PN;
        const float* cre = c_re + layer * PN;
        const float* cim = c_im + layer * PN;
        const float* lst = log_step + layer * Hdim;
        float2* data = (float2*)smem;            // floats [0,8192)
        float4* pol0 = (float4*)(smem + 8192);   // (lam.x, lam.y, u0.x, u0.y)
        float4* pol1 = (float4*)(smem + 8448);   // (v0.x, v0.y, u1.x, u1.y)
        float4* pol2 = (float4*)(smem + 8704);   // (v1.x, v1.y, u2.x, u2.y)
        float4* pol3 = (float4*)(smem + 8960);   // (v2.x, v2.y, w3.x, w3.y)
        float* ktmp = smem + 8192;               // born after fft8 (overlay)
        int baseP = hh * Npol;
        if (t < Npol) {
            int n = t;
            float lr = lre[baseP + n], li = lim[baseP + n];
            float pr = pre[baseP + n], pi = pim[baseP + n];
            float br = bre[baseP + n], bi = bim[baseP + n];
            float cr = cre[baseP + n], ci = cim[baseP + n];
            float cbr = cr * br + ci * bi, cbi = cr * bi - ci * br;
            float cpr = cr * pr + ci * pi, cpi = cr * pi - ci * pr;
            float pbr = pr * br + pi * bi, pbi = pr * bi - pi * br;
            float n11 = pr * pr + pi * pi;
            pol0[n] = make_float4(lr, li, cbr, cbi);
            pol1[n] = make_float4(cbi, -cbr, cpr, cpi);
            pol2[n] = make_float4(cpi, -cpr, pbr, pbi);
            pol3[n] = make_float4(pbi, -pbr, n11, -n11);
        }
        __syncthreads();
        {   // ---- Cauchy spectrum: packed f32 pairs, 4 l-positions/thread ----
            float step = expf(lst[hh]);
            float gs = 2.0f / step;
            float wrv[4], wiv[4];
            f32x2 g[4];
#pragma unroll
            for (int j = 0; j < 4; j++) {
                int l = t + 512 * j;
                float ang = -6.283185307179586f * (float)l / (float)Lseq;
                float wr = cosf(ang), wi = sinf(ang);  // fp32 trig on purpose
                wrv[j] = wr; wiv[j] = wi;
                float dr = 1.0f + wr, di = wi;
                float invd2 = fast_rcp(dr * dr + di * di);
                float nr = 1.0f - wr, ni = -wi;
                g[j].x = gs * (nr * dr + ni * di) * invd2;
                g[j].y = gs * (ni * dr - nr * di) * invd2;
            }
            f32x2 a00[4], a01[4], a10[4], a11[4];
#pragma unroll
            for (int j = 0; j < 4; j++) {
                a00[j] = (f32x2)(0.f); a01[j] = (f32x2)(0.f);
                a10[j] = (f32x2)(0.f); a11[j] = (f32x2)(0.f);
            }
            for (int n = 0; n < Npol; n++) {
                float4 P0 = pol0[n];
                float4 P1 = pol1[n];
                float4 P2 = pol2[n];
                float4 P3 = pol3[n];
                f32x2 lam; lam.x = P0.x; lam.y = P0.y;
                f32x2 u0; u0.x = P0.z; u0.y = P0.w;
                f32x2 v0; v0.x = P1.x; v0.y = P1.y;
                f32x2 u1; u1.x = P1.z; u1.y = P1.w;
                f32x2 v1; v1.x = P2.x; v1.y = P2.y;
                f32x2 u2; u2.x = P2.z; u2.y = P2.w;
                f32x2 v2; v2.x = P3.x; v2.y = P3.y;
                f32x2 w3; w3.x = P3.z; w3.y = P3.w;
#pragma unroll
                for (int j = 0; j < 4; j++) {
                    f32x2 e = g[j] - lam;
                    float inv2 = fast_rcp(fmaf(e.x, e.x, e.y * e.y));
                    f32x2 irmi = e * inv2;
                    f32x2 irb = (f32x2)(irmi.x);
                    f32x2 mib = (f32x2)(irmi.y);
                    a00[j] = u0 * irb + (v0 * mib + a00[j]);
                    a01[j] = u1 * irb + (v1 * mib + a01[j]);
                    a10[j] = u2 * irb + (v2 * mib + a10[j]);
                    a11[j] = w3 * irmi + a11[j];
                }
            }
#pragma unroll
            for (int j = 0; j < 4; j++) {
                int l = t + 512 * j;
                float dr = 1.0f + wrv[j], di = wiv[j];
                float invd2 = fast_rcp(dr * dr + di * di);
                float cr2 = 2.0f * dr * invd2, ci2 = -2.0f * di * invd2;
                float wr2 = 1.0f + a11[j].x, wi2 = a11[j].y;
                float w2inv = fast_rcp(fmaf(wr2, wr2, wi2 * wi2));
                float vr = wr2 * w2inv, vi = -wi2 * w2inv;
                float t1x = a01[j].x * a10[j].x - a01[j].y * a10[j].y;
                float t1y = a01[j].x * a10[j].y + a01[j].y * a10[j].x;
                float t2x = t1x * vr - t1y * vi, t2y = t1x * vi + t1y * vr;
                float ex = a00[j].x - t2x, ey = a00[j].y - t2y;
                data[sw(l)] = make_float2(cr2 * ex - ci2 * ey, cr2 * ey + ci2 * ex);
            }
        }
        __syncthreads();
        if (t < 128) {
            float2 v[16];
#pragma unroll
            for (int k = 0; k < 16; k++) v[k] = data[sw(t + 128 * k)];
            fft16_dif<true>(v);
#pragma unroll
            for (int i = 1; i < 16; i++) v[i] = cmulc(v[i], twget(tw, 2 * t * BR4[i]));
#pragma unroll
            for (int i = 0; i < 16; i++) data[sw(i * 128 + t)] = v[i];
        }
        __syncthreads();
        if (t < 128) {
            int i2 = t >> 3, j0 = t & 7;
            int base2 = i2 * 128 + j0;
            float2 v[16];
#pragma unroll
            for (int k = 0; k < 16; k++) v[k] = data[sw(base2 + 8 * k)];
            fft16_dif<true>(v);
#pragma unroll
            for (int i = 1; i < 16; i++) v[i] = cmulc(v[i], twget(tw, 32 * j0 * BR4[i]));
#pragma unroll
            for (int i = 0; i < 16; i++) data[sw(base2 + 8 * i)] = v[i];
        }
        __syncthreads();
        if (t < 256) {
            float2 v8[8];
#pragma unroll
            for (int k = 0; k < 8; k++) v8[k] = data[sw(t * 8 + k)];
            fft8_dif<true>(v8);
            int r = BR4[t >> 4], s = BR4[t & 15];
#pragma unroll
            for (int i = 0; i < 8; i++) {
                int l = r + 16 * s + 256 * BR3[i];
                ktmp[l] = v8[i].x * (1.0f / 2048.0f);
            }
        }
        __syncthreads();
        if (t < 256) {
            float2 vin[8];
#pragma unroll
            for (int k = 0; k < 8; k++) vin[k] = make_float2(ktmp[t + 256 * k], 0.f);
            fft4096_passA_hz(data, tw, t, vin);
        }
        __syncthreads();
        if (t < 256) fft4096_fwd_B(data, tw, t);
        __syncthreads();
        if (t < 256) fft4096_fwd_C(data, t);
        __syncthreads();
        float2* dst = Kd1 + ((size_t)layer * Hdim + hh) * 4096;
#pragma unroll
        for (int k = 0; k < 8; k++) {
            int p = t + 512 * k;
            dst[p] = data[sw(p)];
        }
    } else {
        // ---- encoder via bf16 MFMA + fused LN: 32 rows/block, t<256 active ----
        int r0 = (bid - 512) * 32;
        __bf16* ybf = (__bf16*)smem;              // 32*72 bf16
        float* dots = smem + 1152;                // 32*132 floats
        float2* mv = (float2*)(smem + 5376);      // 32 float2
        int bb = r0 >> 11, l0 = r0 & 2047;
        for (int i = t; i < 32 * 64; i += 512) {
            int r = i >> 6, k = i & 63;
            ybf[r * 72 + k] = (__bf16)x[(size_t)(r0 + r) * 64 + k];
        }
        __syncthreads();
        if (t < 256) {
            int wave = t >> 6, lane = t & 63;
            int m = lane & 31, half = lane >> 5;
            bf16x8 a[4];
#pragma unroll
            for (int kk = 0; kk < 4; kk++)
                a[kk] = *(const bf16x8*)&ybf[m * 72 + kk * 16 + half * 8];
            int o = 32 * wave + m;
            const __bf16* wr = encbf + (size_t)o * 64 + half * 8;
            f32x16 acc;
#pragma unroll
            for (int i = 0; i < 16; i++) acc[i] = 0.f;
#pragma unroll
            for (int kk = 0; kk < 4; kk++) {
                bf16x8 bw = *(const bf16x8*)(wr + kk * 16);
                acc = __builtin_amdgcn_mfma_f32_32x32x16_bf16(a[kk], bw, acc, 0, 0, 0);
            }
            float bo = enc_b[o];
#pragma unroll
            for (int reg = 0; reg < 16; reg++) {
                int row = (reg & 3) + 8 * (reg >> 2) + 4 * half;
                dots[row * 132 + o] = acc[reg] + bo;
            }
        }
        __syncthreads();
        if (t < 256) {
            int row = t >> 3, lane8 = t & 7;
            float s1 = 0.f, s2 = 0.f;
            int base = row * 132 + lane8 * 16;
#pragma unroll
            for (int q = 0; q < 4; q++) {
                float4 v4 = *(const float4*)&dots[base + 4 * q];
                s1 += v4.x + v4.y + v4.z + v4.w;
                s2 += v4.x * v4.x + v4.y * v4.y + v4.z * v4.z + v4.w * v4.w;
            }
#pragma unroll
            for (int mm = 1; mm < 8; mm <<= 1) { s1 += __shfl_xor(s1, mm); s2 += __shfl_xor(s2, mm); }
            if (lane8 == 0) {
                float mu = s1 * (1.0f / 128.0f);
                float var = s2 * (1.0f / 128.0f) - mu * mu;
                mv[row] = make_float2(mu, fast_rsq(var + 1e-5f));
            }
        }
        __syncthreads();
        if (t < 256) {
            int o2 = t & 127, rh = t >> 7;
            float nwc = nw[o2], nbc = nb[o2];
            float hnv[16];
#pragma unroll
            for (int j = 0; j < 16; j++) {
                int r = rh * 16 + j;
                float hvv = dots[r * 132 + o2];
                h[(size_t)(r0 + r) * Hdim + o2] = hvv;
                float2 mvv = mv[r];
                hnv[j] = (hvv - mvv.x) * mvv.y * nwc + nbc;
            }
            float* dst = hnT + ((size_t)bb * Hdim + o2) * Lseq + l0 + rh * 16;
            *(float4*)(dst)      = make_float4(hnv[0],  hnv[1],  hnv[2],  hnv[3]);
            *(float4*)(dst + 4)  = make_float4(hnv[4],  hnv[5],  hnv[6],  hnv[7]);
            *(float4*)(dst + 8)  = make_float4(hnv[8],  hnv[9],  hnv[10], hnv[11]);
            *(float4*)(dst + 12) = make_float4(hnv[12], hnv[13], hnv[14], hnv[15]);
        }
    }
}

// ---------------- FFT convolution: batch-pair packing, radix-16^3 ----------------
// Output y written as bf16 (its only consumer is the MLP's bf16 A-operand).
__global__ __launch_bounds__(256) void conv_kernel(const float* __restrict__ hnT,
                                                   __bf16* __restrict__ ybuf,
                                                   const float2* __restrict__ Kd1,
                                                   const float* __restrict__ dvec,
                                                   const float2* __restrict__ tw) {
    int h = blockIdx.x, bp = blockIdx.y, t = threadIdx.x;
    __shared__ float2 data[4096];
    const float* u0 = hnT + ((size_t)(2 * bp) * Hdim + h) * Lseq;
    const float* u1 = hnT + ((size_t)(2 * bp + 1) * Hdim + h) * Lseq;
    __bf16* y0 = ybuf + ((size_t)(2 * bp) * Hdim + h) * Lseq;
    __bf16* y1 = ybuf + ((size_t)(2 * bp + 1) * Hdim + h) * Lseq;
    float2 ureg[8];
    float2 Kreg[16];
    float2 twB[15];
    const int j0 = t & 15;
    const float4* Kp4 = (const float4*)(Kd1 + (size_t)h * 4096 + t * 16);
    {   // pruned pass A: input upper half zero, from registers. Kd + B-twiddle
        // prefetch issued alongside the u loads so latency hides under the fwd FFT.
        float2 vin[8];
#pragma unroll
        for (int k = 0; k < 8; k++) {
            int l = t + 256 * k;
            float2 u2 = make_float2(u0[l], u1[l]);
            ureg[k] = u2;
            vin[k] = u2;
        }
#pragma unroll
        for (int k = 0; k < 8; k++) {
            float4 q = Kp4[k];
            Kreg[2 * k]     = make_float2(q.x, q.y);
            Kreg[2 * k + 1] = make_float2(q.z, q.w);
        }
#pragma unroll
        for (int i = 1; i < 16; i++) twB[i - 1] = twget(tw, 16 * j0 * BR4[i]);
        fft4096_passA_hz(data, tw, t, vin);
    }
    __syncthreads();
    {   // forward pass B (register twiddles)
        int base = (t >> 4) * 256 + j0;
        float2 v[16];
#pragma unroll
        for (int k = 0; k < 16; k++) v[k] = data[sw(base + 16 * k)];
        fft16_dif<false>(v);
#pragma unroll
        for (int i = 1; i < 16; i++) v[i] = cmulf(v[i], twB[i - 1]);
#pragma unroll
        for (int i = 0; i < 16; i++) data[sw(base + 16 * i)] = v[i];
    }
    __syncthreads();
    {   // fused: forward pass C -> pointwise *Kd*scale -> inverse pass C'
        const float scale = 1.0f / 4096.0f;
        float2 v[16];
#pragma unroll
        for (int k = 0; k < 16; k++) v[k] = data[sw(t * 16 + k)];
        fft16_dif<false>(v);
#pragma unroll
        for (int i = 0; i < 16; i++) {
            float2 W = cmulf(v[i], Kreg[i]);
            v[i] = make_float2(W.x * scale, W.y * scale);
        }
        fft16_dit<true>(v);
#pragma unroll
        for (int i = 0; i < 16; i++) data[sw(t * 16 + i)] = v[i];
    }
    __syncthreads();
    {   // inverse pass B' (register twiddles, conjugated)
        int base2 = (t >> 4) * 256 + j0;
        float2 v[16];
        v[0] = data[sw(base2)];
#pragma unroll
        for (int i = 1; i < 16; i++)
            v[i] = cmulc(data[sw(base2 + 16 * i)], twB[i - 1]);
        fft16_dit<true>(v);
#pragma unroll
        for (int i = 0; i < 16; i++) data[sw(base2 + 16 * i)] = v[i];
    }
    __syncthreads();
    {   // inverse pass A': final stage pruned to the needed output half (l < 2048)
        float2 v[16];
        v[0] = data[sw(t)];
#pragma unroll
        for (int i = 1; i < 16; i++)
            v[i] = cmulc(data[sw(i * 256 + t)], twget(tw, t * BR4[i]));
#pragma unroll
        for (int mi = 3; mi >= 1; mi--) {
            const int m = 8 >> mi;
#pragma unroll
            for (int g = 0; g < 16; g += 2 * m) {
#pragma unroll
                for (int j = 0; j < m; j++) {
                    float wr = W16R[j << mi], wi = -W16I[j << mi];
                    float2 a = v[g + j], bb2 = v[g + j + m];
                    float bx = bb2.x * wr - bb2.y * wi, by = bb2.x * wi + bb2.y * wr;
                    v[g + j] = make_float2(a.x + bx, a.y + by);
                    v[g + j + m] = make_float2(a.x - bx, a.y - by);
                }
            }
        }
#pragma unroll
        for (int j = 0; j < 8; j++) {
            float wr = W16R[j], wi = -W16I[j];
            float2 bb2 = v[j + 8];
            float bx = bb2.x * wr - bb2.y * wi, by = bb2.x * wi + bb2.y * wr;
            v[j] = make_float2(v[j].x + bx, v[j].y + by);
        }
        float dcoef = dvec[h];
#pragma unroll
        for (int k = 0; k < 8; k++) {
            int l = t + 256 * k;
            y0[l] = (__bf16)gelu_f(v[k].x + ureg[k].x * dcoef);
            y1[l] = (__bf16)gelu_f(v[k].y + ureg[k].y * dcoef);
        }
    }
}

// ---------------- gated MLP via bf16 MFMA, 8-wave split + residual + fused LN ----------------
// Waves 0-3: w1 GEMM -> dots1; waves 4-7: w2 GEMM -> dots2. Gate phase combines
// (same op order as the old fused form -> bit-identical). LN reduce + hnT write
// keep the exact 256-thread code under t<256.
__global__ __launch_bounds__(512) void mlp_kernel(const __bf16* __restrict__ yT,
                                                  float* __restrict__ h,
                                                  float* __restrict__ hnT,
                                                  const __bf16* __restrict__ w1b,
                                                  const __bf16* __restrict__ w2b,
                                                  const float* __restrict__ b1,
                                                  const float* __restrict__ b2,
                                                  const float* __restrict__ nw,
                                                  const float* __restrict__ nb) {
    int r0 = blockIdx.x * 32;
    int t = threadIdx.x;
    int wave = t >> 6, lane = t & 63;
    __shared__ __align__(16) __bf16 ybf[32 * 136];
    __shared__ float dots1[32 * 132];
    __shared__ float dots2[32 * 132];
    __shared__ float2 mv[32];
    int bb = r0 >> 11, l0 = r0 & 2047;
    for (int i = t; i < 32 * 128; i += 512) {
        int r = i & 31, k = i >> 5;
        ybf[r * 136 + k] = yT[((size_t)bb * Hdim + k) * Lseq + l0 + r];
    }
    __syncthreads();
    {
        int m = lane & 31, half = lane >> 5;
        int w = wave & 3, which = wave >> 2;
        bf16x8 a[8];
#pragma unroll
        for (int kk = 0; kk < 8; kk++)
            a[kk] = *(const bf16x8*)&ybf[m * 136 + kk * 16 + half * 8];
        int out = 32 * w + m;
        const __bf16* wr = (which ? w2b : w1b) + (size_t)out * 128 + half * 8;
        f32x16 acc;
#pragma unroll
        for (int i = 0; i < 16; i++) acc[i] = 0.f;
#pragma unroll
        for (int kk = 0; kk < 8; kk++) {
            bf16x8 bw = *(const bf16x8*)(wr + kk * 16);
            acc = __builtin_amdgcn_mfma_f32_32x32x16_bf16(a[kk], bw, acc, 0, 0, 0);
        }
        float bias = which ? b2[out] : b1[out];
        float* dst = which ? dots2 : dots1;
#pragma unroll
        for (int reg = 0; reg < 16; reg++) {
            int row = (reg & 3) + 8 * (reg >> 2) + 4 * half;
            dst[row * 132 + out] = acc[reg] + bias;
        }
    }
    __syncthreads();
    {   // gate + residual: 8 elements/thread, conflict-free (idx = e*512 + t)
#pragma unroll
        for (int e = 0; e < 8; e++) {
            int idx = e * 512 + t;
            int row = idx >> 7, o = idx & 127;
            float v1 = dots1[row * 132 + o];
            float v2 = dots2[row * 132 + o];
            float g = fast_rcp(1.0f + __expf(-v2));
            float hv = h[(size_t)(r0 + row) * Hdim + o] + v1 * g;
            h[(size_t)(r0 + row) * Hdim + o] = hv;
            dots1[row * 132 + o] = hv;
        }
    }
    __syncthreads();
    if (t < 256) {
        int row = t >> 3, lane8 = t & 7;
        float s1 = 0.f, s2 = 0.f;
        int base = row * 132 + lane8 * 16;
#pragma unroll
        for (int q = 0; q < 4; q++) {
            float4 v4 = *(const float4*)&dots1[base + 4 * q];
            s1 += v4.x + v4.y + v4.z + v4.w;
            s2 += v4.x * v4.x + v4.y * v4.y + v4.z * v4.z + v4.w * v4.w;
        }
#pragma unroll
        for (int mm = 1; mm < 8; mm <<= 1) { s1 += __shfl_xor(s1, mm); s2 += __shfl_xor(s2, mm); }
        if (lane8 == 0) {
            float mu = s1 * (1.0f / 128.0f);
            float var = s2 * (1.0f / 128.0f) - mu * mu;
            mv[row] = make_float2(mu, fast_rsq(var + 1e-5f));
        }
    }
    __syncthreads();
    if (t < 256) {
        int o = t & 127, rh = t >> 7;
        float nwc = nw[o], nbc = nb[o];
        float hnv[16];
#pragma unroll
        for (int j = 0; j < 16; j++) {
            int r = rh * 16 + j;
            float hvv = dots1[r * 132 + o];
            float2 mvv = mv[r];
            hnv[j] = (hvv - mvv.x) * mvv.y * nwc + nbc;
        }
        float* dst = hnT + ((size_t)bb * Hdim + o) * Lseq + l0 + rh * 16;
        *(float4*)(dst)      = make_float4(hnv[0],  hnv[1],  hnv[2],  hnv[3]);
        *(float4*)(dst + 4)  = make_float4(hnv[4],  hnv[5],  hnv[6],  hnv[7]);
        *(float4*)(dst + 8)  = make_float4(hnv[8],  hnv[9],  hnv[10], hnv[11]);
        *(float4*)(dst + 12) = make_float4(hnv[12], hnv[13], hnv[14], hnv[15]);
    }
}

// ---------------- last layer: 8-wave gated MLP + residual + fused DECODER ----------
__global__ __launch_bounds__(512) void mlpdec_kernel(const __bf16* __restrict__ yT,
                                                     const float* __restrict__ h,
                                                     const __bf16* __restrict__ w1b,
                                                     const __bf16* __restrict__ w2b,
                                                     const float* __restrict__ b1,
                                                     const float* __restrict__ b2,
                                                     const __bf16* __restrict__ decb,
                                                     const float* __restrict__ dec_bias,
                                                     float* __restrict__ out) {
    int r0 = blockIdx.x * 32;
    int t = threadIdx.x;
    int wave = t >> 6, lane = t & 63;
    __shared__ __align__(16) __bf16 ybf[32 * 136];
    __shared__ float dots1[32 * 132];
    __shared__ float dots2[32 * 132];
    int bb = r0 >> 11, l0 = r0 & 2047;
    for (int i = t; i < 32 * 128; i += 512) {
        int r = i & 31, k = i >> 5;
        ybf[r * 136 + k] = yT[((size_t)bb * Hdim + k) * Lseq + l0 + r];
    }
    __syncthreads();
    int m = lane & 31, half = lane >> 5;
    {
        int w = wave & 3, which = wave >> 2;
        bf16x8 a[8];
#pragma unroll
        for (int kk = 0; kk < 8; kk++)
            a[kk] = *(const bf16x8*)&ybf[m * 136 + kk * 16 + half * 8];
        int outc = 32 * w + m;
        const __bf16* wr = (which ? w2b : w1b) + (size_t)outc * 128 + half * 8;
        f32x16 acc;
#pragma unroll
        for (int i = 0; i < 16; i++) acc[i] = 0.f;
#pragma unroll
        for (int kk = 0; kk < 8; kk++) {
            bf16x8 bw = *(const bf16x8*)(wr + kk * 16);
            acc = __builtin_amdgcn_mfma_f32_32x32x16_bf16(a[kk], bw, acc, 0, 0, 0);
        }
        float bias = which ? b2[outc] : b1[outc];
        float* dst = which ? dots2 : dots1;
#pragma unroll
        for (int reg = 0; reg < 16; reg++) {
            int row = (reg & 3) + 8 * (reg >> 2) + 4 * half;
            dst[row * 132 + outc] = acc[reg] + bias;
        }
    }
    __syncthreads();
    {   // gate + residual into dots1 (no h write on last layer)
#pragma unroll
        for (int e = 0; e < 8; e++) {
            int idx = e * 512 + t;
            int row = idx >> 7, o = idx & 127;
            float v1 = dots1[row * 132 + o];
            float v2 = dots2[row * 132 + o];
            float g = fast_rcp(1.0f + __expf(-v2));
            float hv = h[(size_t)(r0 + row) * Hdim + o] + v1 * g;
            dots1[row * 132 + o] = hv;
        }
    }
    __syncthreads();
    // restage h tile as bf16 A-operands
    for (int i = t; i < 32 * 128; i += 512) {
        int r = i >> 7, k = i & 127;
        ybf[r * 136 + k] = (__bf16)dots1[r * 132 + k];
    }
    __syncthreads();
    if (wave < 2) {  // decoder GEMM: 32 rows x 64 outs, K=128
        bf16x8 a2[8];
#pragma unroll
        for (int kk = 0; kk < 8; kk++)
            a2[kk] = *(const bf16x8*)&ybf[m * 136 + kk * 16 + half * 8];
        int oc = 32 * wave + m;  // 0..63
        const __bf16* wr = decb + (size_t)oc * 128 + half * 8;
        f32x16 acc;
#pragma unroll
        for (int i = 0; i < 16; i++) acc[i] = 0.f;
#pragma unroll
        for (int kk = 0; kk < 8; kk++) {
            bf16x8 bw = *(const bf16x8*)(wr + kk * 16);
            acc = __builtin_amdgcn_mfma_f32_32x32x16_bf16(a2[kk], bw, acc, 0, 0, 0);
        }
        float bo = dec_bias[oc];
#pragma unroll
        for (int reg = 0; reg < 16; reg++) {
            int row = (reg & 3) + 8 * (reg >> 2) + 4 * half;
            out[(size_t)(r0 + row) * 64 + oc] = acc[reg] + bo;
        }
    }
}

extern "C" void kernel_launch(void* const* d_in, const int* in_sizes, int n_in,
                              void* d_out, int out_size, void* d_ws, size_t ws_size,
                              hipStream_t stream) {
    const float* x      = (const float*)d_in[0];
    const float* enc_w  = (const float*)d_in[2];
    const float* enc_b  = (const float*)d_in[3];
    const float* dec_w  = (const float*)d_in[4];
    const float* dec_b  = (const float*)d_in[5];
    const float* lam_re = (const float*)d_in[6];
    const float* lam_im = (const float*)d_in[7];
    const float* p_re   = (const float*)d_in[8];
    const float* p_im   = (const float*)d_in[9];
    const float* b_re   = (const float*)d_in[10];
    const float* b_im   = (const float*)d_in[11];
    const float* c_re   = (const float*)d_in[12];
    const float* c_im   = (const float*)d_in[13];
    const float* dvec   = (const float*)d_in[14];
    const float* lstep  = (const float*)d_in[15];
    const float* norm_w = (const float*)d_in[16];
    const float* norm_b = (const float*)d_in[17];
    const float* w1     = (const float*)d_in[18];
    const float* b1     = (const float*)d_in[19];
    const float* w2     = (const float*)d_in[20];
    const float* b2     = (const float*)d_in[21];
    float* out = (float*)d_out;

    char* ws = (char*)d_ws;
    float2* tw  = (float2*)ws;  ws += 2048 * sizeof(float2);
    float*  h   = (float*)ws;   ws += (size_t)Bsz * Lseq * Hdim * sizeof(float);
    float*  hnT = (float*)ws;   ws += (size_t)Bsz * Lseq * Hdim * sizeof(float);
    __bf16* ybuf = (__bf16*)ws; ws += (size_t)Bsz * Lseq * Hdim * sizeof(__bf16);
    float2* Kd1 = (float2*)ws;  ws += (size_t)NLAYERS * Hdim * 4096 * sizeof(float2);
    __bf16* wbf = (__bf16*)ws;  ws += (size_t)NLAYERS * 2 * Hdim * Hdim * sizeof(__bf16);
    __bf16* dbf = (__bf16*)ws;  ws += (size_t)64 * Hdim * sizeof(__bf16);
    __bf16* ebf = (__bf16*)ws;  ws += (size_t)Hdim * 64 * sizeof(__bf16);

    const int nrows = Bsz * Lseq;  // 16384

    prep_kernel<<<328, 256, 0, stream>>>(w1, w2, dec_w, enc_w, tw, wbf, dbf, ebf);
    kfft_enc_kernel<<<512 + nrows / 32, 512, 0, stream>>>(
        Kd1, tw, x, ebf, enc_b, norm_w, norm_b, h, hnT,
        lam_re, lam_im, p_re, p_im, b_re, b_im, c_re, c_im, lstep);
    for (int L = 0; L < NLAYERS; L++) {
        conv_kernel<<<dim3(Hdim, Bsz / 2), 256, 0, stream>>>(
            hnT, ybuf, Kd1 + (size_t)L * Hdim * 4096, dvec + L * Hdim, tw);
        const __bf16* w1bL = wbf + (size_t)L * 2 * Hdim * Hdim;
        const __bf16* w2bL = w1bL + Hdim * Hdim;
        if (L < NLAYERS - 1) {
            const float* nwn = norm_w + (L + 1) * Hdim;
            const float* nbn = norm_b + (L + 1) * Hdim;
            mlp_kernel<<<nrows / 32, 512, 0, stream>>>(ybuf, h, hnT, w1bL, w2bL,
                                                       b1 + L * Hdim, b2 + L * Hdim,
                                                       nwn, nbn);
        } else {
            mlpdec_kernel<<<nrows / 32, 512, 0, stream>>>(ybuf, h, w1bL, w2bL,
                                                          b1 + L * Hdim, b2 + L * Hdim,
                                                          dbf, dec_b, out);
        }
    }
}